// Round 1
// baseline (18057.997 us; speedup 1.0000x reference)
//
#include <hip/hip_runtime.h>
#include <cmath>

// ---- problem constants ----
#define BATCH 32
#define IMG 224
#define PATCH 16
#define D_MODEL 768
#define DEPTH 12
#define D_STATE 16
#define D_CONV 4
#define D_INNER 1536
#define DT_RANK 48
#define NUM_CLASSES 1000
#define LSEQ 196           // 14*14
#define BL (BATCH * LSEQ)  // 6272
#define BLD ((size_t)BL * D_MODEL)
#define BLDI ((size_t)BL * D_INNER)

// =====================================================================
// Generic fp32 GEMM: C[M,N] = act( A[M,K] * W[N,K]^T + bias + res )
// 64x64 tile, 16 k-tile, 256 threads, 4x4 per thread.
// =====================================================================
#define TM 64
#define TN 64
#define TK 16

__global__ __launch_bounds__(256) void gemm_f32(
    const float* __restrict__ A, int lda,
    const float* __restrict__ W,       // N x K, row-major
    const float* __restrict__ bias,    // len N or null
    const float* __restrict__ res,     // M x ldc or null (added)
    float* __restrict__ C, int ldc,
    int M, int N, int K, int act)      // act: 0 none, 1 softplus
{
    __shared__ float As[TK][TM + 4];
    __shared__ float Ws[TK][TN + 4];
    const int m0 = blockIdx.x * TM;
    const int n0 = blockIdx.y * TN;
    const int t = threadIdx.x;
    const int tm = (t & 15) * 4;
    const int tn = (t >> 4) * 4;

    float acc[4][4] = {};

    for (int k0 = 0; k0 < K; k0 += TK) {
#pragma unroll
        for (int i = 0; i < 4; i++) {
            int e = t + i * 256;
            int ml = e >> 4, kl = e & 15;
            int m = m0 + ml;
            As[kl][ml] = (m < M) ? A[(size_t)m * lda + k0 + kl] : 0.f;
        }
#pragma unroll
        for (int i = 0; i < 4; i++) {
            int e = t + i * 256;
            int nl = e >> 4, kl = e & 15;
            int n = n0 + nl;
            Ws[kl][nl] = (n < N) ? W[(size_t)n * K + k0 + kl] : 0.f;
        }
        __syncthreads();
#pragma unroll
        for (int k = 0; k < TK; k++) {
            float a[4], w[4];
#pragma unroll
            for (int i = 0; i < 4; i++) a[i] = As[k][tm + i];
#pragma unroll
            for (int j = 0; j < 4; j++) w[j] = Ws[k][tn + j];
#pragma unroll
            for (int i = 0; i < 4; i++)
#pragma unroll
                for (int j = 0; j < 4; j++)
                    acc[i][j] = fmaf(a[i], w[j], acc[i][j]);
        }
        __syncthreads();
    }

#pragma unroll
    for (int i = 0; i < 4; i++) {
        int m = m0 + tm + i;
        if (m >= M) continue;
#pragma unroll
        for (int j = 0; j < 4; j++) {
            int n = n0 + tn + j;
            if (n >= N) continue;
            float c = acc[i][j];
            if (bias) c += bias[n];
            if (res) c += res[(size_t)m * ldc + n];
            if (act == 1) c = (c > 20.f) ? c : log1pf(expf(c));
            C[(size_t)m * ldc + n] = c;
        }
    }
}

// =====================================================================
// im2col for the 16x16 stride-16 patch conv. out[m][k], m=b*196+l,
// k=c*256+kh*16+kw  (matches patch_w (768,3,16,16) row-major flatten)
// =====================================================================
__global__ __launch_bounds__(256) void im2col_patch(
    const float* __restrict__ x, float* __restrict__ out)
{
    size_t idx = (size_t)blockIdx.x * 256 + threadIdx.x;
    if (idx >= BLD) return;
    int m = (int)(idx / D_MODEL);
    int k = (int)(idx % D_MODEL);
    int b = m / LSEQ, l = m % LSEQ;
    int ph = l / 14, pw = l % 14;
    int c = k >> 8, r = k & 255;
    int kh = r >> 4, kw = r & 15;
    out[idx] = x[(((size_t)b * 3 + c) * IMG + ph * PATCH + kh) * IMG + pw * PATCH + kw];
}

// =====================================================================
// LayerNorm over last dim (768). One block per (b,l) row.
// =====================================================================
__global__ __launch_bounds__(256) void layernorm_768(
    const float* __restrict__ x, const float* __restrict__ g,
    const float* __restrict__ b, float* __restrict__ o)
{
    __shared__ float red[4];
    const size_t base = (size_t)blockIdx.x * D_MODEL;
    const int t = threadIdx.x;

    float v[3];
#pragma unroll
    for (int i = 0; i < 3; i++) v[i] = x[base + t + i * 256];

    float s = v[0] + v[1] + v[2];
#pragma unroll
    for (int off = 32; off > 0; off >>= 1) s += __shfl_down(s, off);
    if ((t & 63) == 0) red[t >> 6] = s;
    __syncthreads();
    float mu = (red[0] + red[1] + red[2] + red[3]) * (1.f / D_MODEL);
    __syncthreads();

    float q = 0.f;
#pragma unroll
    for (int i = 0; i < 3; i++) { float d = v[i] - mu; q += d * d; }
#pragma unroll
    for (int off = 32; off > 0; off >>= 1) q += __shfl_down(q, off);
    if ((t & 63) == 0) red[t >> 6] = q;
    __syncthreads();
    float var = (red[0] + red[1] + red[2] + red[3]) * (1.f / D_MODEL);
    float rs = rsqrtf(var + 1e-5f);

#pragma unroll
    for (int i = 0; i < 3; i++) {
        int d = t + i * 256;
        o[base + d] = (v[i] - mu) * rs * g[d] + b[d];
    }
}

// =====================================================================
// depthwise causal conv1d (k=4, left pad 3) + SiLU
// =====================================================================
__global__ __launch_bounds__(256) void conv1d_silu(
    const float* __restrict__ xi, const float* __restrict__ cw,
    const float* __restrict__ cb, float* __restrict__ xc)
{
    size_t idx = (size_t)blockIdx.x * 256 + threadIdx.x;
    if (idx >= BLDI) return;
    int m = (int)(idx / D_INNER);
    int e = (int)(idx % D_INNER);
    int b = m / LSEQ, l = m % LSEQ;
    float s = cb[e];
#pragma unroll
    for (int k = 0; k < D_CONV; k++) {
        int ll = l + k - (D_CONV - 1);
        if (ll >= 0)
            s = fmaf(xi[((size_t)b * LSEQ + ll) * D_INNER + e], cw[e * D_CONV + k], s);
    }
    xc[idx] = s / (1.f + expf(-s));
}

// =====================================================================
// Selective scan. One lane per (b, d, s). 16-lane shfl reduce for y.
// Writes y in place of xc (safe: same element, same wave, same step).
// grid (D_INNER/16, BATCH), block 256 = 16 d x 16 s.
// =====================================================================
__global__ __launch_bounds__(256) void selective_scan(
    const float* __restrict__ dt, const float* __restrict__ xc,
    const float* __restrict__ z, const float* __restrict__ dbl,
    const float* __restrict__ A_log, const float* __restrict__ Dp,
    float* __restrict__ y)
{
    const int t = threadIdx.x;
    const int s = t & 15;
    const int d = blockIdx.x * 16 + (t >> 4);
    const int b = blockIdx.y;

    const float a = -expf(A_log[d * D_STATE + s]);
    const float dp = Dp[d];
    const float* dblb = dbl + (size_t)b * LSEQ * 80;
    const size_t base = (size_t)b * LSEQ * D_INNER + d;

    float h = 0.f;
    for (int l = 0; l < LSEQ; l++) {
        const size_t off = base + (size_t)l * D_INNER;
        float dtv = dt[off];
        float xv = xc[off];
        float Bv = dblb[l * 80 + DT_RANK + s];
        float Cv = dblb[l * 80 + DT_RANK + D_STATE + s];
        float dA = __expf(dtv * a);
        h = fmaf(dA, h, dtv * Bv * xv);
        float py = h * Cv;
        py += __shfl_xor(py, 1);
        py += __shfl_xor(py, 2);
        py += __shfl_xor(py, 4);
        py += __shfl_xor(py, 8);
        if (s == 0) {
            float zv = z[off];
            float yv = py + dp * xv;
            y[off] = yv * zv / (1.f + expf(-zv));
        }
    }
}

// =====================================================================
// mean over L: pooled[b][d] = mean_l hn[b,l,d]
// =====================================================================
__global__ __launch_bounds__(256) void pool_mean(
    const float* __restrict__ hn, float* __restrict__ pooled)
{
    int d = blockIdx.x * 256 + threadIdx.x;
    int b = blockIdx.y;
    if (d >= D_MODEL) return;
    float s = 0.f;
    for (int l = 0; l < LSEQ; l++)
        s += hn[((size_t)b * LSEQ + l) * D_MODEL + d];
    pooled[(size_t)b * D_MODEL + d] = s * (1.f / LSEQ);
}

// =====================================================================
static inline void gemm_launch(hipStream_t st, const float* A, int lda,
                               const float* W, const float* bias,
                               const float* res, float* C, int ldc,
                               int M, int N, int K, int act)
{
    dim3 g((M + TM - 1) / TM, (N + TN - 1) / TN);
    gemm_f32<<<g, 256, 0, st>>>(A, lda, W, bias, res, C, ldc, M, N, K, act);
}

extern "C" void kernel_launch(void* const* d_in, const int* in_sizes, int n_in,
                              void* d_out, int out_size, void* d_ws, size_t ws_size,
                              hipStream_t stream)
{
    const float* x       = (const float*)d_in[0];
    const float* patch_w = (const float*)d_in[1];
    const float* patch_b = (const float*)d_in[2];
    const float* ln_g    = (const float*)d_in[3];
    const float* ln_b    = (const float*)d_in[4];
    const float* in_w    = (const float*)d_in[5];
    const float* conv_w  = (const float*)d_in[6];
    const float* conv_b  = (const float*)d_in[7];
    const float* xp_w    = (const float*)d_in[8];
    const float* dt_w    = (const float*)d_in[9];
    const float* dt_b    = (const float*)d_in[10];
    const float* A_log   = (const float*)d_in[11];
    const float* Dp      = (const float*)d_in[12];
    const float* out_w   = (const float*)d_in[13];
    const float* fn_g    = (const float*)d_in[14];
    const float* fn_b    = (const float*)d_in[15];
    const float* head_w  = (const float*)d_in[16];
    const float* head_b  = (const float*)d_in[17];
    float* out = (float*)d_out;

    float* ws = (float*)d_ws;
    float* h      = ws;            // BL x 768
    float* hn     = h + BLD;       // BL x 768 (also im2col buffer)
    float* xi     = hn + BLD;      // BL x 1536
    float* zb     = xi + BLDI;     // BL x 1536
    float* xc     = zb + BLDI;     // BL x 1536
    float* dblbuf = xc + BLDI;     // BL x 80
    float* pooled = dblbuf + (size_t)BL * 80;  // 32 x 768
    float* dtbuf  = xi;            // reuse: xi dead after conv
    float* ybuf   = xc;            // in-place over xc in scan

    // ---- patch embed ----
    im2col_patch<<<(unsigned)((BLD + 255) / 256), 256, 0, stream>>>(x, hn);
    gemm_launch(stream, hn, D_MODEL, patch_w, patch_b, nullptr, h, D_MODEL,
                BL, D_MODEL, D_MODEL, 0);

    // ---- mamba blocks ----
    for (int layer = 0; layer < DEPTH; layer++) {
        const float* lg  = ln_g + (size_t)layer * D_MODEL;
        const float* lb  = ln_b + (size_t)layer * D_MODEL;
        const float* iw  = in_w + (size_t)layer * 2 * D_INNER * D_MODEL;
        const float* cw  = conv_w + (size_t)layer * D_INNER * D_CONV;
        const float* cb  = conv_b + (size_t)layer * D_INNER;
        const float* xw  = xp_w + (size_t)layer * (DT_RANK + 2 * D_STATE) * D_INNER;
        const float* dw  = dt_w + (size_t)layer * D_INNER * DT_RANK;
        const float* db  = dt_b + (size_t)layer * D_INNER;
        const float* al  = A_log + (size_t)layer * D_INNER * D_STATE;
        const float* dpp = Dp + (size_t)layer * D_INNER;
        const float* ow  = out_w + (size_t)layer * D_MODEL * D_INNER;

        layernorm_768<<<BL, 256, 0, stream>>>(h, lg, lb, hn);

        // in_proj: rows 0..1535 -> xi, rows 1536..3071 -> z
        gemm_launch(stream, hn, D_MODEL, iw, nullptr, nullptr, xi, D_INNER,
                    BL, D_INNER, D_MODEL, 0);
        gemm_launch(stream, hn, D_MODEL, iw + (size_t)D_INNER * D_MODEL,
                    nullptr, nullptr, zb, D_INNER, BL, D_INNER, D_MODEL, 0);

        conv1d_silu<<<(unsigned)((BLDI + 255) / 256), 256, 0, stream>>>(xi, cw, cb, xc);

        // x_proj -> dbl (BL x 80)
        gemm_launch(stream, xc, D_INNER, xw, nullptr, nullptr, dblbuf, 80,
                    BL, DT_RANK + 2 * D_STATE, D_INNER, 0);

        // dt = softplus(dbl[:, :48] @ dt_w^T + dt_b)  (writes over xi)
        gemm_launch(stream, dblbuf, 80, dw, db, nullptr, dtbuf, D_INNER,
                    BL, D_INNER, DT_RANK, 1);

        // selective scan (+ Dp*xc, * silu(z)), y in place of xc
        dim3 sg(D_INNER / 16, BATCH);
        selective_scan<<<sg, 256, 0, stream>>>(dtbuf, xc, zb, dblbuf, al, dpp, ybuf);

        // out_proj + residual -> h
        gemm_launch(stream, ybuf, D_INNER, ow, nullptr, h, h, D_MODEL,
                    BL, D_MODEL, D_INNER, 0);
    }

    // ---- final LN + mean + head ----
    layernorm_768<<<BL, 256, 0, stream>>>(h, fn_g, fn_b, hn);
    dim3 pg(3, BATCH);
    pool_mean<<<pg, 256, 0, stream>>>(hn, pooled);
    gemm_launch(stream, pooled, D_MODEL, head_w, head_b, nullptr, out, NUM_CLASSES,
                BATCH, NUM_CLASSES, D_MODEL, 0);
}

// Round 2
// 7267.766 us; speedup vs baseline: 2.4847x; 2.4847x over previous
//
#include <hip/hip_runtime.h>
#include <cmath>

// ---- problem constants ----
#define BATCH 32
#define IMG 224
#define PATCHSZ 16
#define D_MODEL 768
#define DEPTH 12
#define D_STATE 16
#define D_CONV 4
#define D_INNER 1536
#define DT_RANK 48
#define NUM_CLASSES 1000
#define LSEQ 196           // 14*14
#define BL (BATCH * LSEQ)  // 6272
#define BLD ((size_t)BL * D_MODEL)
#define BLDI ((size_t)BL * D_INNER)
#define XP_PAD 128         // x_proj N padded 80 -> 128

typedef __attribute__((ext_vector_type(8))) short bf16x8_t;
typedef __attribute__((ext_vector_type(4))) float f32x4_t;

__device__ __forceinline__ float bf2f(unsigned short u) {
    union { unsigned int i; float f; } v; v.i = (unsigned int)u << 16; return v.f;
}
__device__ __forceinline__ unsigned short f2bf(float f) {
    union { float f; unsigned int i; } v; v.f = f;
    unsigned int r = v.i + 0x7FFFu + ((v.i >> 16) & 1u);
    return (unsigned short)(r >> 16);
}

__device__ __forceinline__ void gload16(const unsigned short* g, unsigned short* l) {
    __builtin_amdgcn_global_load_lds(
        (const __attribute__((address_space(1))) void*)g,
        (__attribute__((address_space(3))) void*)l, 16, 0, 0);
}

// =====================================================================
// bf16 MFMA GEMM: C[M,N] = A[M,K] * W[N,K]^T (+bias)(+res), fp32 out.
// REQUIRES: M%128==0, N%128==0, K%64==0, 16B-aligned pointers.
// 128x128 tile, BK=64, 256 threads = 4 waves (2x2), 4x4 16x16 frags/wave.
// =====================================================================
__global__ __launch_bounds__(256) void gemm_bf16(
    const unsigned short* __restrict__ A,   // M x K
    const unsigned short* __restrict__ W,   // N x K
    const float* __restrict__ bias,         // len N or null
    const float* __restrict__ res, int ldr, // M x ldr or null
    float* __restrict__ C, int ldc,
    int K)
{
    __shared__ unsigned short lds[2 * 128 * 64];   // 32 KiB: A tile, B tile
    unsigned short* As = lds;
    unsigned short* Bs = lds + 128 * 64;

    const int t = threadIdx.x;
    const int m0 = blockIdx.x * 128;
    const int n0 = blockIdx.y * 128;
    const int lane = t & 63;
    const int w = t >> 6;
    const int wm = w >> 1, wn = w & 1;

    // staging: thread t covers 16B at tile elem e = r*2048 + t*8
    const int srow = t >> 3;           // 0..31 (+32 per round)
    const int scol = (t & 7) * 8;
    const unsigned short* Ag = A + (size_t)(m0 + srow) * K + scol;
    const unsigned short* Wg = W + (size_t)(n0 + srow) * K + scol;
    unsigned short* Al = As + t * 8;
    unsigned short* Bl = Bs + t * 8;

    f32x4_t acc[4][4];
#pragma unroll
    for (int i = 0; i < 4; i++)
#pragma unroll
        for (int j = 0; j < 4; j++)
            acc[i][j] = (f32x4_t){0.f, 0.f, 0.f, 0.f};

    const int lr = lane & 15;          // fragment row/col within 16
    const int lk = (lane >> 4) * 8;    // k-octet base

    for (int k0 = 0; k0 < K; k0 += 64) {
        __syncthreads();               // prev tile fully consumed
#pragma unroll
        for (int r = 0; r < 4; r++) {
            gload16(Ag + (size_t)r * 32 * K + k0, Al + r * 2048);
            gload16(Wg + (size_t)r * 32 * K + k0, Bl + r * 2048);
        }
        __syncthreads();               // drains vmcnt before barrier
#pragma unroll
        for (int ks = 0; ks < 2; ks++) {
            const int ko = ks * 32 + lk;
            bf16x8_t af[4], bfr[4];
#pragma unroll
            for (int i = 0; i < 4; i++)
                af[i] = *(const bf16x8_t*)&As[(wm * 64 + i * 16 + lr) * 64 + ko];
#pragma unroll
            for (int j = 0; j < 4; j++)
                bfr[j] = *(const bf16x8_t*)&Bs[(wn * 64 + j * 16 + lr) * 64 + ko];
#pragma unroll
            for (int i = 0; i < 4; i++)
#pragma unroll
                for (int j = 0; j < 4; j++)
                    acc[i][j] = __builtin_amdgcn_mfma_f32_16x16x32_bf16(
                        af[i], bfr[j], acc[i][j], 0, 0, 0);
        }
    }

    // epilogue: C/D layout col=lane&15, row=(lane>>4)*4+q
#pragma unroll
    for (int i = 0; i < 4; i++) {
        const int row = m0 + wm * 64 + i * 16 + (lane >> 4) * 4;
#pragma unroll
        for (int j = 0; j < 4; j++) {
            const int col = n0 + wn * 64 + j * 16 + lr;
            const float bv = bias ? bias[col] : 0.f;
#pragma unroll
            for (int q = 0; q < 4; q++) {
                float v = acc[i][j][q] + bv;
                if (res) v += res[(size_t)(row + q) * ldr + col];
                C[(size_t)(row + q) * ldc + col] = v;
            }
        }
    }
}

// =====================================================================
// fp32 GEMM (kept for dt-proj K=48 and head): C = act(A*W^T + bias + res)
// =====================================================================
#define TM 64
#define TN 64
#define TK 16

__global__ __launch_bounds__(256) void gemm_f32(
    const float* __restrict__ A, int lda,
    const float* __restrict__ W,
    const float* __restrict__ bias,
    const float* __restrict__ res,
    float* __restrict__ C, int ldc,
    int M, int N, int K, int act)
{
    __shared__ float As[TK][TM + 4];
    __shared__ float Ws[TK][TN + 4];
    const int m0 = blockIdx.x * TM;
    const int n0 = blockIdx.y * TN;
    const int t = threadIdx.x;
    const int tm = (t & 15) * 4;
    const int tn = (t >> 4) * 4;

    float acc[4][4] = {};

    for (int k0 = 0; k0 < K; k0 += TK) {
#pragma unroll
        for (int i = 0; i < 4; i++) {
            int e = t + i * 256;
            int ml = e >> 4, kl = e & 15;
            int m = m0 + ml;
            As[kl][ml] = (m < M) ? A[(size_t)m * lda + k0 + kl] : 0.f;
        }
#pragma unroll
        for (int i = 0; i < 4; i++) {
            int e = t + i * 256;
            int nl = e >> 4, kl = e & 15;
            int n = n0 + nl;
            Ws[kl][nl] = (n < N) ? W[(size_t)n * K + k0 + kl] : 0.f;
        }
        __syncthreads();
#pragma unroll
        for (int k = 0; k < TK; k++) {
            float a[4], wv[4];
#pragma unroll
            for (int i = 0; i < 4; i++) a[i] = As[k][tm + i];
#pragma unroll
            for (int j = 0; j < 4; j++) wv[j] = Ws[k][tn + j];
#pragma unroll
            for (int i = 0; i < 4; i++)
#pragma unroll
                for (int j = 0; j < 4; j++)
                    acc[i][j] = fmaf(a[i], wv[j], acc[i][j]);
        }
        __syncthreads();
    }

#pragma unroll
    for (int i = 0; i < 4; i++) {
        int m = m0 + tm + i;
        if (m >= M) continue;
#pragma unroll
        for (int j = 0; j < 4; j++) {
            int n = n0 + tn + j;
            if (n >= N) continue;
            float c = acc[i][j];
            if (bias) c += bias[n];
            if (res) c += res[(size_t)m * ldc + n];
            if (act == 1) c = (c > 20.f) ? c : log1pf(expf(c));
            C[(size_t)m * ldc + n] = c;
        }
    }
}

// =====================================================================
// casts
// =====================================================================
__global__ __launch_bounds__(256) void cast_bf16_v4(
    const float* __restrict__ in, unsigned short* __restrict__ out, int n4)
{
    int i = blockIdx.x * 256 + threadIdx.x;
    if (i >= n4) return;
    float4 v = ((const float4*)in)[i];
    ushort4 o;
    o.x = f2bf(v.x); o.y = f2bf(v.y); o.z = f2bf(v.z); o.w = f2bf(v.w);
    ((ushort4*)out)[i] = o;
}

// xp_w (80 x 1536) -> padded (128 x 1536) bf16, rows 80..127 zero
__global__ __launch_bounds__(256) void cast_xp_pad(
    const float* __restrict__ in, unsigned short* __restrict__ out)
{
    int idx = blockIdx.x * 256 + threadIdx.x;   // over 128*1536
    if (idx >= XP_PAD * D_INNER) return;
    int n = idx / D_INNER, k = idx % D_INNER;
    out[idx] = (n < (DT_RANK + 2 * D_STATE)) ? f2bf(in[n * D_INNER + k]) : 0;
}

// =====================================================================
// im2col (bf16 out) for 16x16 stride-16 patch conv
// =====================================================================
__global__ __launch_bounds__(256) void im2col_patch_bf16(
    const float* __restrict__ x, unsigned short* __restrict__ out)
{
    size_t idx = (size_t)blockIdx.x * 256 + threadIdx.x;
    if (idx >= BLD) return;
    int m = (int)(idx / D_MODEL);
    int k = (int)(idx % D_MODEL);
    int b = m / LSEQ, l = m % LSEQ;
    int ph = l / 14, pw = l % 14;
    int c = k >> 8, r = k & 255;
    int kh = r >> 4, kw = r & 15;
    out[idx] = f2bf(x[(((size_t)b * 3 + c) * IMG + ph * PATCHSZ + kh) * IMG + pw * PATCHSZ + kw]);
}

// =====================================================================
// LayerNorm over last dim (768). One block per (b,l) row.
// =====================================================================
template <bool BF16OUT>
__global__ __launch_bounds__(256) void layernorm_768(
    const float* __restrict__ x, const float* __restrict__ g,
    const float* __restrict__ b, void* __restrict__ optr)
{
    __shared__ float red[4];
    const size_t base = (size_t)blockIdx.x * D_MODEL;
    const int t = threadIdx.x;

    float v[3];
#pragma unroll
    for (int i = 0; i < 3; i++) v[i] = x[base + t + i * 256];

    float s = v[0] + v[1] + v[2];
#pragma unroll
    for (int off = 32; off > 0; off >>= 1) s += __shfl_down(s, off);
    if ((t & 63) == 0) red[t >> 6] = s;
    __syncthreads();
    float mu = (red[0] + red[1] + red[2] + red[3]) * (1.f / D_MODEL);
    __syncthreads();

    float q = 0.f;
#pragma unroll
    for (int i = 0; i < 3; i++) { float d = v[i] - mu; q += d * d; }
#pragma unroll
    for (int off = 32; off > 0; off >>= 1) q += __shfl_down(q, off);
    if ((t & 63) == 0) red[t >> 6] = q;
    __syncthreads();
    float var = (red[0] + red[1] + red[2] + red[3]) * (1.f / D_MODEL);
    float rs = rsqrtf(var + 1e-5f);

#pragma unroll
    for (int i = 0; i < 3; i++) {
        int d = t + i * 256;
        float o = (v[i] - mu) * rs * g[d] + b[d];
        if (BF16OUT) ((unsigned short*)optr)[base + d] = f2bf(o);
        else         ((float*)optr)[base + d] = o;
    }
}

// =====================================================================
// depthwise causal conv1d (k=4) + SiLU. xi rows stride 3072 (xz cols 0..1535).
// =====================================================================
__global__ __launch_bounds__(256) void conv1d_silu(
    const float* __restrict__ xi, const float* __restrict__ cw,
    const float* __restrict__ cb, unsigned short* __restrict__ xc)
{
    size_t idx = (size_t)blockIdx.x * 256 + threadIdx.x;
    if (idx >= BLDI) return;
    int m = (int)(idx / D_INNER);
    int e = (int)(idx % D_INNER);
    int b = m / LSEQ, l = m % LSEQ;
    float s = cb[e];
#pragma unroll
    for (int k = 0; k < D_CONV; k++) {
        int ll = l + k - (D_CONV - 1);
        if (ll >= 0)
            s = fmaf(xi[((size_t)b * LSEQ + ll) * 3072 + e], cw[e * D_CONV + k], s);
    }
    xc[idx] = f2bf(s / (1.f + expf(-s)));
}

// =====================================================================
// Selective scan. One lane per (b,d,s). dt/z fp32 stride 3072, xc bf16
// read + y bf16 written in place. dbl stride 128 (B at 48, C at 64).
// =====================================================================
__global__ __launch_bounds__(256) void selective_scan(
    const float* __restrict__ dt,      // xz cols 0..1535, stride 3072
    unsigned short* xc,                // [BL][1536] bf16, in/out (y)
    const float* __restrict__ z,       // xz + 1536, stride 3072
    const float* __restrict__ dbl,     // [BL][128]
    const float* __restrict__ A_log, const float* __restrict__ Dp)
{
    const int t = threadIdx.x;
    const int s = t & 15;
    const int d = blockIdx.x * 16 + (t >> 4);
    const int b = blockIdx.y;

    const float a = -expf(A_log[d * D_STATE + s]);
    const float dp = Dp[d];
    const float* dblb = dbl + (size_t)b * LSEQ * XP_PAD;
    const size_t row0 = (size_t)b * LSEQ;

    float h = 0.f;
    for (int l = 0; l < LSEQ; l++) {
        const size_t row = row0 + l;
        const size_t offw = row * 3072 + d;       // dt / z
        const size_t offx = row * D_INNER + d;    // xc / y
        float dtv = dt[offw];
        float xv = bf2f(xc[offx]);
        float Bv = dblb[l * XP_PAD + DT_RANK + s];
        float Cv = dblb[l * XP_PAD + DT_RANK + D_STATE + s];
        float dA = __expf(dtv * a);
        h = fmaf(dA, h, dtv * Bv * xv);
        float py = h * Cv;
        py += __shfl_xor(py, 1);
        py += __shfl_xor(py, 2);
        py += __shfl_xor(py, 4);
        py += __shfl_xor(py, 8);
        if (s == 0) {
            float zv = z[offw];
            float yv = py + dp * xv;
            xc[offx] = f2bf(yv * zv / (1.f + expf(-zv)));
        }
    }
}

// =====================================================================
// mean over L
// =====================================================================
__global__ __launch_bounds__(256) void pool_mean(
    const float* __restrict__ hn, float* __restrict__ pooled)
{
    int d = blockIdx.x * 256 + threadIdx.x;
    int b = blockIdx.y;
    if (d >= D_MODEL) return;
    float s = 0.f;
    for (int l = 0; l < LSEQ; l++)
        s += hn[((size_t)b * LSEQ + l) * D_MODEL + d];
    pooled[(size_t)b * D_MODEL + d] = s * (1.f / LSEQ);
}

// =====================================================================
static inline void gemm32(hipStream_t st, const float* A, int lda,
                          const float* W, const float* bias,
                          const float* res, float* C, int ldc,
                          int M, int N, int K, int act)
{
    dim3 g((M + TM - 1) / TM, (N + TN - 1) / TN);
    gemm_f32<<<g, 256, 0, st>>>(A, lda, W, bias, res, C, ldc, M, N, K, act);
}

static inline void gemmbf(hipStream_t st, const unsigned short* A,
                          const unsigned short* W, const float* bias,
                          const float* res, int ldr, float* C, int ldc,
                          int M, int N, int K)
{
    dim3 g(M / 128, N / 128);
    gemm_bf16<<<g, 256, 0, st>>>(A, W, bias, res, ldr, C, ldc, K);
}

extern "C" void kernel_launch(void* const* d_in, const int* in_sizes, int n_in,
                              void* d_out, int out_size, void* d_ws, size_t ws_size,
                              hipStream_t stream)
{
    const float* x       = (const float*)d_in[0];
    const float* patch_w = (const float*)d_in[1];
    const float* patch_b = (const float*)d_in[2];
    const float* ln_g    = (const float*)d_in[3];
    const float* ln_b    = (const float*)d_in[4];
    const float* in_w    = (const float*)d_in[5];
    const float* conv_w  = (const float*)d_in[6];
    const float* conv_b  = (const float*)d_in[7];
    const float* xp_w    = (const float*)d_in[8];
    const float* dt_w    = (const float*)d_in[9];
    const float* dt_b    = (const float*)d_in[10];
    const float* A_log   = (const float*)d_in[11];
    const float* Dp      = (const float*)d_in[12];
    const float* out_w   = (const float*)d_in[13];
    const float* fn_g    = (const float*)d_in[14];
    const float* fn_b    = (const float*)d_in[15];
    const float* head_w  = (const float*)d_in[16];
    const float* head_b  = (const float*)d_in[17];
    float* out = (float*)d_out;

    // ---- workspace layout (~137 MB) ----
    float* wf = (float*)d_ws;
    float* h      = wf;                           // BL x 768
    float* xz     = h + BLD;                      // BL x 3072 (xi|z; dt reuses xi; final-LN out)
    float* dbl    = xz + (size_t)BL * 3072;       // BL x 128
    float* pooled = dbl + (size_t)BL * XP_PAD;    // 32 x 768
    unsigned short* us = (unsigned short*)(pooled + (size_t)BATCH * D_MODEL);
    unsigned short* hn_bf   = us;                             // BL x 768 (also im2col buf)
    unsigned short* xc_bf   = hn_bf + BLD;                    // BL x 1536 (xc, then y in place)
    unsigned short* w_in_bf = xc_bf + BLDI;                   // 3072 x 768
    unsigned short* w_out_bf= w_in_bf + (size_t)2 * D_INNER * D_MODEL;   // 768 x 1536
    unsigned short* w_xp_bf = w_out_bf + (size_t)D_MODEL * D_INNER;      // 128 x 1536 (padded)
    unsigned short* w_pt_bf = w_xp_bf + (size_t)XP_PAD * D_INNER;        // 768 x 768

    float* dtbuf = xz;          // dt overwrites xi (xz cols 0..1535)
    float* zptr  = xz + D_INNER;
    float* fln   = xz;          // final LN output (xz free then)

    // ---- patch embed ----
    cast_bf16_v4<<<(D_MODEL * D_MODEL / 4 + 255) / 256, 256, 0, stream>>>(
        patch_w, w_pt_bf, D_MODEL * D_MODEL / 4);
    im2col_patch_bf16<<<(unsigned)((BLD + 255) / 256), 256, 0, stream>>>(x, hn_bf);
    gemmbf(stream, hn_bf, w_pt_bf, patch_b, nullptr, 0, h, D_MODEL,
           BL, D_MODEL, D_MODEL);

    // ---- mamba blocks ----
    for (int layer = 0; layer < DEPTH; layer++) {
        const float* lg  = ln_g + (size_t)layer * D_MODEL;
        const float* lb  = ln_b + (size_t)layer * D_MODEL;
        const float* iw  = in_w + (size_t)layer * 2 * D_INNER * D_MODEL;
        const float* cw  = conv_w + (size_t)layer * D_INNER * D_CONV;
        const float* cb  = conv_b + (size_t)layer * D_INNER;
        const float* xw  = xp_w + (size_t)layer * (DT_RANK + 2 * D_STATE) * D_INNER;
        const float* dw  = dt_w + (size_t)layer * D_INNER * DT_RANK;
        const float* db  = dt_b + (size_t)layer * D_INNER;
        const float* al  = A_log + (size_t)layer * D_INNER * D_STATE;
        const float* dpp = Dp + (size_t)layer * D_INNER;
        const float* ow  = out_w + (size_t)layer * D_MODEL * D_INNER;

        // cast this layer's weights
        cast_bf16_v4<<<(2 * D_INNER * D_MODEL / 4 + 255) / 256, 256, 0, stream>>>(
            iw, w_in_bf, 2 * D_INNER * D_MODEL / 4);
        cast_bf16_v4<<<(D_MODEL * D_INNER / 4 + 255) / 256, 256, 0, stream>>>(
            ow, w_out_bf, D_MODEL * D_INNER / 4);
        cast_xp_pad<<<(XP_PAD * D_INNER + 255) / 256, 256, 0, stream>>>(xw, w_xp_bf);

        // LN -> bf16
        layernorm_768<true><<<BL, 256, 0, stream>>>(h, lg, lb, hn_bf);

        // in_proj (one GEMM, N=3072) -> xz fp32
        gemmbf(stream, hn_bf, w_in_bf, nullptr, nullptr, 0, xz, 2 * D_INNER,
               BL, 2 * D_INNER, D_MODEL);

        // conv + silu -> xc bf16
        conv1d_silu<<<(unsigned)((BLDI + 255) / 256), 256, 0, stream>>>(xz, cw, cb, xc_bf);

        // x_proj -> dbl fp32 (N padded to 128)
        gemmbf(stream, xc_bf, w_xp_bf, nullptr, nullptr, 0, dbl, XP_PAD,
               BL, XP_PAD, D_INNER);

        // dt = softplus(dbl[:, :48] @ dt_w^T + dt_b) -> xz cols 0..1535
        gemm32(stream, dbl, XP_PAD, dw, db, nullptr, dtbuf, 2 * D_INNER,
               BL, D_INNER, DT_RANK, 1);

        // selective scan (+Dp*xc, *silu(z)); y bf16 in place of xc
        dim3 sg(D_INNER / 16, BATCH);
        selective_scan<<<sg, 256, 0, stream>>>(dtbuf, xc_bf, zptr, dbl, al, dpp);

        // out_proj + residual -> h
        gemmbf(stream, xc_bf, w_out_bf, nullptr, h, D_MODEL, h, D_MODEL,
               BL, D_MODEL, D_INNER);
    }

    // ---- final LN + mean + head ----
    layernorm_768<false><<<BL, 256, 0, stream>>>(h, fn_g, fn_b, fln);
    dim3 pg(3, BATCH);
    pool_mean<<<pg, 256, 0, stream>>>(fln, pooled);
    gemm32(stream, pooled, D_MODEL, head_w, head_b, nullptr, out, NUM_CLASSES,
           BATCH, NUM_CLASSES, D_MODEL, 0);
}

// Round 3
// 4724.667 us; speedup vs baseline: 3.8221x; 1.5383x over previous
//
#include <hip/hip_runtime.h>
#include <cmath>

// ---- problem constants ----
#define BATCH 32
#define IMG 224
#define PATCHSZ 16
#define D_MODEL 768
#define DEPTH 12
#define D_STATE 16
#define D_CONV 4
#define D_INNER 1536
#define DT_RANK 48
#define NUM_CLASSES 1000
#define LSEQ 196           // 14*14
#define BL (BATCH * LSEQ)  // 6272
#define BLD ((size_t)BL * D_MODEL)
#define BLDI ((size_t)BL * D_INNER)
#define XP_PAD 128         // x_proj N padded 80 -> 128

typedef __attribute__((ext_vector_type(8))) short bf16x8_t;
typedef __attribute__((ext_vector_type(4))) float f32x4_t;

__device__ __forceinline__ float bf2f(unsigned short u) {
    union { unsigned int i; float f; } v; v.i = (unsigned int)u << 16; return v.f;
}
__device__ __forceinline__ unsigned short f2bf(float f) {
    union { float f; unsigned int i; } v; v.f = f;
    unsigned int r = v.i + 0x7FFFu + ((v.i >> 16) & 1u);
    return (unsigned short)(r >> 16);
}

__device__ __forceinline__ void gload16(const unsigned short* g, unsigned short* l) {
    __builtin_amdgcn_global_load_lds(
        (const __attribute__((address_space(1))) void*)g,
        (__attribute__((address_space(3))) void*)l, 16, 0, 0);
}

// =====================================================================
// bf16 MFMA GEMM: C[M,N] = A[M,K] * W[N,K]^T (+bias)(+res), fp32 out.
// REQUIRES: M%128==0, N%128==0, K%64==0, 16B-aligned pointers.
// 128x128 tile, BK=64, 256 threads = 4 waves (2x2), 4x4 16x16 frags/wave.
// XCD-aware bijective block swizzle (m204).
// =====================================================================
__global__ __launch_bounds__(256) void gemm_bf16(
    const unsigned short* __restrict__ A,   // M x K
    const unsigned short* __restrict__ W,   // N x K
    const float* __restrict__ bias,         // len N or null
    const float* __restrict__ res, int ldr, // M x ldr or null
    float* __restrict__ C, int ldc,
    int K)
{
    __shared__ unsigned short lds[2 * 128 * 64];   // 32 KiB: A tile, B tile
    unsigned short* As = lds;
    unsigned short* Bs = lds + 128 * 64;

    // ---- bijective XCD swizzle: consecutive wgid -> same XCD ----
    const int gx = gridDim.x;
    const int nwg = gx * gridDim.y;
    int orig = blockIdx.x + blockIdx.y * gx;
    {
        int q = nwg >> 3, r = nwg & 7;
        int xcd = orig & 7, idx = orig >> 3;
        orig = (xcd < r ? xcd * (q + 1) : r * (q + 1) + (xcd - r) * q) + idx;
    }
    const int m0 = (orig % gx) * 128;
    const int n0 = (orig / gx) * 128;

    const int t = threadIdx.x;
    const int lane = t & 63;
    const int w = t >> 6;
    const int wm = w >> 1, wn = w & 1;

    // staging: thread t covers 16B at tile elem e = r*2048 + t*8
    const int srow = t >> 3;           // 0..31 (+32 per round)
    const int scol = (t & 7) * 8;
    const unsigned short* Ag = A + (size_t)(m0 + srow) * K + scol;
    const unsigned short* Wg = W + (size_t)(n0 + srow) * K + scol;
    unsigned short* Al = As + t * 8;
    unsigned short* Bl = Bs + t * 8;

    f32x4_t acc[4][4];
#pragma unroll
    for (int i = 0; i < 4; i++)
#pragma unroll
        for (int j = 0; j < 4; j++)
            acc[i][j] = (f32x4_t){0.f, 0.f, 0.f, 0.f};

    const int lr = lane & 15;          // fragment row/col within 16
    const int lk = (lane >> 4) * 8;    // k-octet base

    for (int k0 = 0; k0 < K; k0 += 64) {
        __syncthreads();               // prev tile fully consumed
#pragma unroll
        for (int r = 0; r < 4; r++) {
            gload16(Ag + (size_t)r * 32 * K + k0, Al + r * 2048);
            gload16(Wg + (size_t)r * 32 * K + k0, Bl + r * 2048);
        }
        __syncthreads();               // drains vmcnt before barrier
#pragma unroll
        for (int ks = 0; ks < 2; ks++) {
            const int ko = ks * 32 + lk;
            bf16x8_t af[4], bfr[4];
#pragma unroll
            for (int i = 0; i < 4; i++)
                af[i] = *(const bf16x8_t*)&As[(wm * 64 + i * 16 + lr) * 64 + ko];
#pragma unroll
            for (int j = 0; j < 4; j++)
                bfr[j] = *(const bf16x8_t*)&Bs[(wn * 64 + j * 16 + lr) * 64 + ko];
#pragma unroll
            for (int i = 0; i < 4; i++)
#pragma unroll
                for (int j = 0; j < 4; j++)
                    acc[i][j] = __builtin_amdgcn_mfma_f32_16x16x32_bf16(
                        af[i], bfr[j], acc[i][j], 0, 0, 0);
        }
    }

    // epilogue: C/D layout col=lane&15, row=(lane>>4)*4+q
#pragma unroll
    for (int i = 0; i < 4; i++) {
        const int row = m0 + wm * 64 + i * 16 + (lane >> 4) * 4;
#pragma unroll
        for (int j = 0; j < 4; j++) {
            const int col = n0 + wn * 64 + j * 16 + lr;
            const float bv = bias ? bias[col] : 0.f;
#pragma unroll
            for (int q = 0; q < 4; q++) {
                float v = acc[i][j][q] + bv;
                if (res) v += res[(size_t)(row + q) * ldr + col];
                C[(size_t)(row + q) * ldc + col] = v;
            }
        }
    }
}

// =====================================================================
// fp32 GEMM (kept for dt-proj K=48 and head): C = act(A*W^T + bias + res)
// =====================================================================
#define TM 64
#define TN 64
#define TK 16

__global__ __launch_bounds__(256) void gemm_f32(
    const float* __restrict__ A, int lda,
    const float* __restrict__ W,
    const float* __restrict__ bias,
    const float* __restrict__ res,
    float* __restrict__ C, int ldc,
    int M, int N, int K, int act)
{
    __shared__ float As[TK][TM + 4];
    __shared__ float Ws[TK][TN + 4];
    const int m0 = blockIdx.x * TM;
    const int n0 = blockIdx.y * TN;
    const int t = threadIdx.x;
    const int tm = (t & 15) * 4;
    const int tn = (t >> 4) * 4;

    float acc[4][4] = {};

    for (int k0 = 0; k0 < K; k0 += TK) {
#pragma unroll
        for (int i = 0; i < 4; i++) {
            int e = t + i * 256;
            int ml = e >> 4, kl = e & 15;
            int m = m0 + ml;
            As[kl][ml] = (m < M) ? A[(size_t)m * lda + k0 + kl] : 0.f;
        }
#pragma unroll
        for (int i = 0; i < 4; i++) {
            int e = t + i * 256;
            int nl = e >> 4, kl = e & 15;
            int n = n0 + nl;
            Ws[kl][nl] = (n < N) ? W[(size_t)n * K + k0 + kl] : 0.f;
        }
        __syncthreads();
#pragma unroll
        for (int k = 0; k < TK; k++) {
            float a[4], wv[4];
#pragma unroll
            for (int i = 0; i < 4; i++) a[i] = As[k][tm + i];
#pragma unroll
            for (int j = 0; j < 4; j++) wv[j] = Ws[k][tn + j];
#pragma unroll
            for (int i = 0; i < 4; i++)
#pragma unroll
                for (int j = 0; j < 4; j++)
                    acc[i][j] = fmaf(a[i], wv[j], acc[i][j]);
        }
        __syncthreads();
    }

#pragma unroll
    for (int i = 0; i < 4; i++) {
        int m = m0 + tm + i;
        if (m >= M) continue;
#pragma unroll
        for (int j = 0; j < 4; j++) {
            int n = n0 + tn + j;
            if (n >= N) continue;
            float c = acc[i][j];
            if (bias) c += bias[n];
            if (res) c += res[(size_t)m * ldc + n];
            if (act == 1) c = (c > 20.f) ? c : log1pf(expf(c));
            C[(size_t)m * ldc + n] = c;
        }
    }
}

// =====================================================================
// casts
// =====================================================================
__global__ __launch_bounds__(256) void cast_bf16_v4(
    const float* __restrict__ in, unsigned short* __restrict__ out, int n4)
{
    int i = blockIdx.x * 256 + threadIdx.x;
    if (i >= n4) return;
    float4 v = ((const float4*)in)[i];
    ushort4 o;
    o.x = f2bf(v.x); o.y = f2bf(v.y); o.z = f2bf(v.z); o.w = f2bf(v.w);
    ((ushort4*)out)[i] = o;
}

// xp_w (80 x 1536) -> padded (128 x 1536) bf16, rows 80..127 zero
__global__ __launch_bounds__(256) void cast_xp_pad(
    const float* __restrict__ in, unsigned short* __restrict__ out)
{
    int idx = blockIdx.x * 256 + threadIdx.x;   // over 128*1536
    if (idx >= XP_PAD * D_INNER) return;
    int n = idx / D_INNER, k = idx % D_INNER;
    out[idx] = (n < (DT_RANK + 2 * D_STATE)) ? f2bf(in[n * D_INNER + k]) : 0;
}

// =====================================================================
// im2col (bf16 out) for 16x16 stride-16 patch conv
// =====================================================================
__global__ __launch_bounds__(256) void im2col_patch_bf16(
    const float* __restrict__ x, unsigned short* __restrict__ out)
{
    size_t idx = (size_t)blockIdx.x * 256 + threadIdx.x;
    if (idx >= BLD) return;
    int m = (int)(idx / D_MODEL);
    int k = (int)(idx % D_MODEL);
    int b = m / LSEQ, l = m % LSEQ;
    int ph = l / 14, pw = l % 14;
    int c = k >> 8, r = k & 255;
    int kh = r >> 4, kw = r & 15;
    out[idx] = f2bf(x[(((size_t)b * 3 + c) * IMG + ph * PATCHSZ + kh) * IMG + pw * PATCHSZ + kw]);
}

// =====================================================================
// LayerNorm over last dim (768). One block per (b,l) row.
// =====================================================================
template <bool BF16OUT>
__global__ __launch_bounds__(256) void layernorm_768(
    const float* __restrict__ x, const float* __restrict__ g,
    const float* __restrict__ b, void* __restrict__ optr)
{
    __shared__ float red[4];
    const size_t base = (size_t)blockIdx.x * D_MODEL;
    const int t = threadIdx.x;

    float v[3];
#pragma unroll
    for (int i = 0; i < 3; i++) v[i] = x[base + t + i * 256];

    float s = v[0] + v[1] + v[2];
#pragma unroll
    for (int off = 32; off > 0; off >>= 1) s += __shfl_down(s, off);
    if ((t & 63) == 0) red[t >> 6] = s;
    __syncthreads();
    float mu = (red[0] + red[1] + red[2] + red[3]) * (1.f / D_MODEL);
    __syncthreads();

    float q = 0.f;
#pragma unroll
    for (int i = 0; i < 3; i++) { float d = v[i] - mu; q += d * d; }
#pragma unroll
    for (int off = 32; off > 0; off >>= 1) q += __shfl_down(q, off);
    if ((t & 63) == 0) red[t >> 6] = q;
    __syncthreads();
    float var = (red[0] + red[1] + red[2] + red[3]) * (1.f / D_MODEL);
    float rs = rsqrtf(var + 1e-5f);

#pragma unroll
    for (int i = 0; i < 3; i++) {
        int d = t + i * 256;
        float o = (v[i] - mu) * rs * g[d] + b[d];
        if (BF16OUT) ((unsigned short*)optr)[base + d] = f2bf(o);
        else         ((float*)optr)[base + d] = o;
    }
}

// =====================================================================
// depthwise causal conv1d (k=4) + SiLU. xi rows stride 3072 (xz cols 0..1535).
// =====================================================================
__global__ __launch_bounds__(256) void conv1d_silu(
    const float* __restrict__ xi, const float* __restrict__ cw,
    const float* __restrict__ cb, unsigned short* __restrict__ xc)
{
    size_t idx = (size_t)blockIdx.x * 256 + threadIdx.x;
    if (idx >= BLDI) return;
    int m = (int)(idx / D_INNER);
    int e = (int)(idx % D_INNER);
    int b = m / LSEQ, l = m % LSEQ;
    float s = cb[e];
#pragma unroll
    for (int k = 0; k < D_CONV; k++) {
        int ll = l + k - (D_CONV - 1);
        if (ll >= 0)
            s = fmaf(xi[((size_t)b * LSEQ + ll) * 3072 + e], cw[e * D_CONV + k], s);
    }
    xc[idx] = f2bf(s / (1.f + expf(-s)));
}

// =====================================================================
// Selective scan v2: 4 states/lane, 4 lanes per channel, software
// prefetch by 1 step. Wave covers 16 channels. Writes y (bf16) in
// place of xc. grid (D_INNER/64, BATCH), block 256.
// =====================================================================
__global__ __launch_bounds__(256) void selective_scan(
    const float* __restrict__ dt,      // xz cols 0..1535, stride 3072
    unsigned short* xc,                // [BL][1536] bf16, in/out (y)
    const float* __restrict__ z,       // xz + 1536, stride 3072
    const float* __restrict__ dbl,     // [BL][128]
    const float* __restrict__ A_log, const float* __restrict__ Dp)
{
    const int t = threadIdx.x;
    const int sg = (t & 3) * 4;                 // state quad base
    const int d = blockIdx.x * 64 + (t >> 2);
    const int b = blockIdx.y;

    const float4 av = *(const float4*)&A_log[d * D_STATE + sg];
    const float a0 = -__expf(av.x), a1 = -__expf(av.y),
                a2 = -__expf(av.z), a3 = -__expf(av.w);
    const float dp = Dp[d];

    const float* dblb = dbl + (size_t)b * LSEQ * XP_PAD;
    const size_t rw0 = (size_t)b * LSEQ * 3072 + d;     // dt/z rows
    const size_t rx0 = (size_t)b * LSEQ * D_INNER + d;  // xc/y rows

    float h0 = 0.f, h1 = 0.f, h2 = 0.f, h3 = 0.f;

    // prefetch l=0
    float dtv = dt[rw0];
    float zv  = z[rw0];
    float xv  = bf2f(xc[rx0]);
    float4 B4 = *(const float4*)&dblb[DT_RANK + sg];
    float4 C4 = *(const float4*)&dblb[DT_RANK + D_STATE + sg];

    for (int l = 0; l < LSEQ; ++l) {
        const float dtc = dtv, xvc = xv, zvc = zv;
        const float4 Bc = B4, Cc = C4;
        if (l + 1 < LSEQ) {                      // prefetch next step
            const size_t ow = rw0 + (size_t)(l + 1) * 3072;
            const size_t ox = rx0 + (size_t)(l + 1) * D_INNER;
            dtv = dt[ow];
            zv  = z[ow];
            xv  = bf2f(xc[ox]);
            B4 = *(const float4*)&dblb[(l + 1) * XP_PAD + DT_RANK + sg];
            C4 = *(const float4*)&dblb[(l + 1) * XP_PAD + DT_RANK + D_STATE + sg];
        }
        const float dtx = dtc * xvc;
        h0 = fmaf(__expf(dtc * a0), h0, dtx * Bc.x);
        h1 = fmaf(__expf(dtc * a1), h1, dtx * Bc.y);
        h2 = fmaf(__expf(dtc * a2), h2, dtx * Bc.z);
        h3 = fmaf(__expf(dtc * a3), h3, dtx * Bc.w);
        float py = fmaf(h0, Cc.x, fmaf(h1, Cc.y, fmaf(h2, Cc.z, h3 * Cc.w)));
        py += __shfl_xor(py, 1);
        py += __shfl_xor(py, 2);
        if ((t & 3) == 0) {
            const float yv = py + dp * xvc;
            const float sig = 1.f / (1.f + __expf(-zvc));
            xc[rx0 + (size_t)l * D_INNER] = f2bf(yv * zvc * sig);
        }
    }
}

// =====================================================================
// mean over L
// =====================================================================
__global__ __launch_bounds__(256) void pool_mean(
    const float* __restrict__ hn, float* __restrict__ pooled)
{
    int d = blockIdx.x * 256 + threadIdx.x;
    int b = blockIdx.y;
    if (d >= D_MODEL) return;
    float s = 0.f;
    for (int l = 0; l < LSEQ; l++)
        s += hn[((size_t)b * LSEQ + l) * D_MODEL + d];
    pooled[(size_t)b * D_MODEL + d] = s * (1.f / LSEQ);
}

// =====================================================================
static inline void gemm32(hipStream_t st, const float* A, int lda,
                          const float* W, const float* bias,
                          const float* res, float* C, int ldc,
                          int M, int N, int K, int act)
{
    dim3 g((M + TM - 1) / TM, (N + TN - 1) / TN);
    gemm_f32<<<g, 256, 0, st>>>(A, lda, W, bias, res, C, ldc, M, N, K, act);
}

static inline void gemmbf(hipStream_t st, const unsigned short* A,
                          const unsigned short* W, const float* bias,
                          const float* res, int ldr, float* C, int ldc,
                          int M, int N, int K)
{
    dim3 g(M / 128, N / 128);
    gemm_bf16<<<g, 256, 0, st>>>(A, W, bias, res, ldr, C, ldc, K);
}

extern "C" void kernel_launch(void* const* d_in, const int* in_sizes, int n_in,
                              void* d_out, int out_size, void* d_ws, size_t ws_size,
                              hipStream_t stream)
{
    const float* x       = (const float*)d_in[0];
    const float* patch_w = (const float*)d_in[1];
    const float* patch_b = (const float*)d_in[2];
    const float* ln_g    = (const float*)d_in[3];
    const float* ln_b    = (const float*)d_in[4];
    const float* in_w    = (const float*)d_in[5];
    const float* conv_w  = (const float*)d_in[6];
    const float* conv_b  = (const float*)d_in[7];
    const float* xp_w    = (const float*)d_in[8];
    const float* dt_w    = (const float*)d_in[9];
    const float* dt_b    = (const float*)d_in[10];
    const float* A_log   = (const float*)d_in[11];
    const float* Dp      = (const float*)d_in[12];
    const float* out_w   = (const float*)d_in[13];
    const float* fn_g    = (const float*)d_in[14];
    const float* fn_b    = (const float*)d_in[15];
    const float* head_w  = (const float*)d_in[16];
    const float* head_b  = (const float*)d_in[17];
    float* out = (float*)d_out;

    // ---- workspace layout (~137 MB) ----
    float* wf = (float*)d_ws;
    float* h      = wf;                           // BL x 768
    float* xz     = h + BLD;                      // BL x 3072 (xi|z; dt reuses xi; final-LN out)
    float* dbl    = xz + (size_t)BL * 3072;       // BL x 128
    float* pooled = dbl + (size_t)BL * XP_PAD;    // 32 x 768
    unsigned short* us = (unsigned short*)(pooled + (size_t)BATCH * D_MODEL);
    unsigned short* hn_bf   = us;                             // BL x 768 (also im2col buf)
    unsigned short* xc_bf   = hn_bf + BLD;                    // BL x 1536 (xc, then y in place)
    unsigned short* w_in_bf = xc_bf + BLDI;                   // 3072 x 768
    unsigned short* w_out_bf= w_in_bf + (size_t)2 * D_INNER * D_MODEL;   // 768 x 1536
    unsigned short* w_xp_bf = w_out_bf + (size_t)D_MODEL * D_INNER;      // 128 x 1536 (padded)
    unsigned short* w_pt_bf = w_xp_bf + (size_t)XP_PAD * D_INNER;        // 768 x 768

    float* dtbuf = xz;          // dt overwrites xi (xz cols 0..1535)
    float* zptr  = xz + D_INNER;
    float* fln   = xz;          // final LN output (xz free then)

    // ---- patch embed ----
    cast_bf16_v4<<<(D_MODEL * D_MODEL / 4 + 255) / 256, 256, 0, stream>>>(
        patch_w, w_pt_bf, D_MODEL * D_MODEL / 4);
    im2col_patch_bf16<<<(unsigned)((BLD + 255) / 256), 256, 0, stream>>>(x, hn_bf);
    gemmbf(stream, hn_bf, w_pt_bf, patch_b, nullptr, 0, h, D_MODEL,
           BL, D_MODEL, D_MODEL);

    // ---- mamba blocks ----
    for (int layer = 0; layer < DEPTH; layer++) {
        const float* lg  = ln_g + (size_t)layer * D_MODEL;
        const float* lb  = ln_b + (size_t)layer * D_MODEL;
        const float* iw  = in_w + (size_t)layer * 2 * D_INNER * D_MODEL;
        const float* cw  = conv_w + (size_t)layer * D_INNER * D_CONV;
        const float* cb  = conv_b + (size_t)layer * D_INNER;
        const float* xw  = xp_w + (size_t)layer * (DT_RANK + 2 * D_STATE) * D_INNER;
        const float* dw  = dt_w + (size_t)layer * D_INNER * DT_RANK;
        const float* db  = dt_b + (size_t)layer * D_INNER;
        const float* al  = A_log + (size_t)layer * D_INNER * D_STATE;
        const float* dpp = Dp + (size_t)layer * D_INNER;
        const float* ow  = out_w + (size_t)layer * D_MODEL * D_INNER;

        // cast this layer's weights
        cast_bf16_v4<<<(2 * D_INNER * D_MODEL / 4 + 255) / 256, 256, 0, stream>>>(
            iw, w_in_bf, 2 * D_INNER * D_MODEL / 4);
        cast_bf16_v4<<<(D_MODEL * D_INNER / 4 + 255) / 256, 256, 0, stream>>>(
            ow, w_out_bf, D_MODEL * D_INNER / 4);
        cast_xp_pad<<<(XP_PAD * D_INNER + 255) / 256, 256, 0, stream>>>(xw, w_xp_bf);

        // LN -> bf16
        layernorm_768<true><<<BL, 256, 0, stream>>>(h, lg, lb, hn_bf);

        // in_proj (one GEMM, N=3072) -> xz fp32
        gemmbf(stream, hn_bf, w_in_bf, nullptr, nullptr, 0, xz, 2 * D_INNER,
               BL, 2 * D_INNER, D_MODEL);

        // conv + silu -> xc bf16
        conv1d_silu<<<(unsigned)((BLDI + 255) / 256), 256, 0, stream>>>(xz, cw, cb, xc_bf);

        // x_proj -> dbl fp32 (N padded to 128)
        gemmbf(stream, xc_bf, w_xp_bf, nullptr, nullptr, 0, dbl, XP_PAD,
               BL, XP_PAD, D_INNER);

        // dt = softplus(dbl[:, :48] @ dt_w^T + dt_b) -> xz cols 0..1535
        gemm32(stream, dbl, XP_PAD, dw, db, nullptr, dtbuf, 2 * D_INNER,
               BL, D_INNER, DT_RANK, 1);

        // selective scan (+Dp*xc, *silu(z)); y bf16 in place of xc
        dim3 sg(D_INNER / 64, BATCH);
        selective_scan<<<sg, 256, 0, stream>>>(dtbuf, xc_bf, zptr, dbl, al, dpp);

        // out_proj + residual -> h
        gemmbf(stream, xc_bf, w_out_bf, nullptr, h, D_MODEL, h, D_MODEL,
               BL, D_MODEL, D_INNER);
    }

    // ---- final LN + mean + head ----
    layernorm_768<false><<<BL, 256, 0, stream>>>(h, fn_g, fn_b, fln);
    dim3 pg(3, BATCH);
    pool_mean<<<pg, 256, 0, stream>>>(fln, pooled);
    gemm32(stream, pooled, D_MODEL, head_w, head_b, nullptr, out, NUM_CLASSES,
           BATCH, NUM_CLASSES, D_MODEL, 0);
}

// Round 4
// 4243.864 us; speedup vs baseline: 4.2551x; 1.1133x over previous
//
#include <hip/hip_runtime.h>
#include <cmath>

// ---- problem constants ----
#define BATCH 32
#define IMG 224
#define PATCHSZ 16
#define D_MODEL 768
#define DEPTH 12
#define D_STATE 16
#define D_CONV 4
#define D_INNER 1536
#define DT_RANK 48
#define NUM_CLASSES 1000
#define LSEQ 196           // 14*14
#define BL (BATCH * LSEQ)  // 6272
#define BLD ((size_t)BL * D_MODEL)
#define BLDI ((size_t)BL * D_INNER)
#define XP_PAD 128         // x_proj N padded 80 -> 128

typedef __attribute__((ext_vector_type(8))) short bf16x8_t;
typedef __attribute__((ext_vector_type(4))) float f32x4_t;

__device__ __forceinline__ float bf2f(unsigned short u) {
    union { unsigned int i; float f; } v; v.i = (unsigned int)u << 16; return v.f;
}
__device__ __forceinline__ unsigned short f2bf(float f) {
    union { float f; unsigned int i; } v; v.f = f;
    unsigned int r = v.i + 0x7FFFu + ((v.i >> 16) & 1u);
    return (unsigned short)(r >> 16);
}

__device__ __forceinline__ void gload16(const void* g, void* l) {
    __builtin_amdgcn_global_load_lds(
        (const __attribute__((address_space(1))) void*)g,
        (__attribute__((address_space(3))) void*)l, 16, 0, 0);
}

// =====================================================================
// bf16 MFMA GEMM: C[M,N] = A[M,K] * W[N,K]^T (+bias)(+res), fp32 out.
// REQUIRES: M%128==0, N%128==0, K%64==0, 16B-aligned pointers.
// 128x128 tile, BK=64, 256 threads = 4 waves (2x2), 4x4 16x16 frags/wave.
// XCD-aware bijective block swizzle (m204).
// =====================================================================
__global__ __launch_bounds__(256) void gemm_bf16(
    const unsigned short* __restrict__ A,   // M x K
    const unsigned short* __restrict__ W,   // N x K
    const float* __restrict__ bias,         // len N or null
    const float* __restrict__ res, int ldr, // M x ldr or null
    float* __restrict__ C, int ldc,
    int K)
{
    __shared__ unsigned short lds[2 * 128 * 64];   // 32 KiB: A tile, B tile
    unsigned short* As = lds;
    unsigned short* Bs = lds + 128 * 64;

    // ---- bijective XCD swizzle: consecutive wgid -> same XCD ----
    const int gx = gridDim.x;
    const int nwg = gx * gridDim.y;
    int orig = blockIdx.x + blockIdx.y * gx;
    {
        int q = nwg >> 3, r = nwg & 7;
        int xcd = orig & 7, idx = orig >> 3;
        orig = (xcd < r ? xcd * (q + 1) : r * (q + 1) + (xcd - r) * q) + idx;
    }
    const int m0 = (orig % gx) * 128;
    const int n0 = (orig / gx) * 128;

    const int t = threadIdx.x;
    const int lane = t & 63;
    const int w = t >> 6;
    const int wm = w >> 1, wn = w & 1;

    // staging: thread t covers 16B at tile elem e = r*2048 + t*8
    const int srow = t >> 3;           // 0..31 (+32 per round)
    const int scol = (t & 7) * 8;
    const unsigned short* Ag = A + (size_t)(m0 + srow) * K + scol;
    const unsigned short* Wg = W + (size_t)(n0 + srow) * K + scol;
    unsigned short* Al = As + t * 8;
    unsigned short* Bl = Bs + t * 8;

    f32x4_t acc[4][4];
#pragma unroll
    for (int i = 0; i < 4; i++)
#pragma unroll
        for (int j = 0; j < 4; j++)
            acc[i][j] = (f32x4_t){0.f, 0.f, 0.f, 0.f};

    const int lr = lane & 15;          // fragment row/col within 16
    const int lk = (lane >> 4) * 8;    // k-octet base

    for (int k0 = 0; k0 < K; k0 += 64) {
        __syncthreads();               // prev tile fully consumed
#pragma unroll
        for (int r = 0; r < 4; r++) {
            gload16(Ag + (size_t)r * 32 * K + k0, Al + r * 2048);
            gload16(Wg + (size_t)r * 32 * K + k0, Bl + r * 2048);
        }
        __syncthreads();               // drains vmcnt before barrier
#pragma unroll
        for (int ks = 0; ks < 2; ks++) {
            const int ko = ks * 32 + lk;
            bf16x8_t af[4], bfr[4];
#pragma unroll
            for (int i = 0; i < 4; i++)
                af[i] = *(const bf16x8_t*)&As[(wm * 64 + i * 16 + lr) * 64 + ko];
#pragma unroll
            for (int j = 0; j < 4; j++)
                bfr[j] = *(const bf16x8_t*)&Bs[(wn * 64 + j * 16 + lr) * 64 + ko];
#pragma unroll
            for (int i = 0; i < 4; i++)
#pragma unroll
                for (int j = 0; j < 4; j++)
                    acc[i][j] = __builtin_amdgcn_mfma_f32_16x16x32_bf16(
                        af[i], bfr[j], acc[i][j], 0, 0, 0);
        }
    }

    // epilogue: C/D layout col=lane&15, row=(lane>>4)*4+q
#pragma unroll
    for (int i = 0; i < 4; i++) {
        const int row = m0 + wm * 64 + i * 16 + (lane >> 4) * 4;
#pragma unroll
        for (int j = 0; j < 4; j++) {
            const int col = n0 + wn * 64 + j * 16 + lr;
            const float bv = bias ? bias[col] : 0.f;
#pragma unroll
            for (int q = 0; q < 4; q++) {
                float v = acc[i][j][q] + bv;
                if (res) v += res[(size_t)(row + q) * ldr + col];
                C[(size_t)(row + q) * ldc + col] = v;
            }
        }
    }
}

// =====================================================================
// fp32 GEMM (kept for dt-proj K=48 and head): C = act(A*W^T + bias + res)
// =====================================================================
#define TM 64
#define TN 64
#define TK 16

__global__ __launch_bounds__(256) void gemm_f32(
    const float* __restrict__ A, int lda,
    const float* __restrict__ W,
    const float* __restrict__ bias,
    const float* __restrict__ res,
    float* __restrict__ C, int ldc,
    int M, int N, int K, int act)
{
    __shared__ float As[TK][TM + 4];
    __shared__ float Ws[TK][TN + 4];
    const int m0 = blockIdx.x * TM;
    const int n0 = blockIdx.y * TN;
    const int t = threadIdx.x;
    const int tm = (t & 15) * 4;
    const int tn = (t >> 4) * 4;

    float acc[4][4] = {};

    for (int k0 = 0; k0 < K; k0 += TK) {
#pragma unroll
        for (int i = 0; i < 4; i++) {
            int e = t + i * 256;
            int ml = e >> 4, kl = e & 15;
            int m = m0 + ml;
            As[kl][ml] = (m < M) ? A[(size_t)m * lda + k0 + kl] : 0.f;
        }
#pragma unroll
        for (int i = 0; i < 4; i++) {
            int e = t + i * 256;
            int nl = e >> 4, kl = e & 15;
            int n = n0 + nl;
            Ws[kl][nl] = (n < N) ? W[(size_t)n * K + k0 + kl] : 0.f;
        }
        __syncthreads();
#pragma unroll
        for (int k = 0; k < TK; k++) {
            float a[4], wv[4];
#pragma unroll
            for (int i = 0; i < 4; i++) a[i] = As[k][tm + i];
#pragma unroll
            for (int j = 0; j < 4; j++) wv[j] = Ws[k][tn + j];
#pragma unroll
            for (int i = 0; i < 4; i++)
#pragma unroll
                for (int j = 0; j < 4; j++)
                    acc[i][j] = fmaf(a[i], wv[j], acc[i][j]);
        }
        __syncthreads();
    }

#pragma unroll
    for (int i = 0; i < 4; i++) {
        int m = m0 + tm + i;
        if (m >= M) continue;
#pragma unroll
        for (int j = 0; j < 4; j++) {
            int n = n0 + tn + j;
            if (n >= N) continue;
            float c = acc[i][j];
            if (bias) c += bias[n];
            if (res) c += res[(size_t)m * ldc + n];
            if (act == 1) c = (c > 20.f) ? c : log1pf(expf(c));
            C[(size_t)m * ldc + n] = c;
        }
    }
}

// =====================================================================
// merged per-layer weight cast: in_w (2*1536x768), out_w (768x1536),
// xp_w (80x1536 -> padded 128x1536). One launch per layer.
// =====================================================================
#define NIN4 (2 * D_INNER * D_MODEL / 4)
#define NOUT4 (D_MODEL * D_INNER / 4)
#define NXP4 (XP_PAD * D_INNER / 4)
#define NCAST4 (NIN4 + NOUT4 + NXP4)   // 933888 = 3648 * 256

__global__ __launch_bounds__(256) void cast_layer(
    const float* __restrict__ iw, const float* __restrict__ ow,
    const float* __restrict__ xw,
    unsigned short* __restrict__ w_in_bf,
    unsigned short* __restrict__ w_out_bf,
    unsigned short* __restrict__ w_xp_bf)
{
    int i = blockIdx.x * 256 + threadIdx.x;
    const float* src; unsigned short* dst; int j;
    if (i < NIN4) { src = iw; dst = w_in_bf; j = i; }
    else if (i < NIN4 + NOUT4) { src = ow; dst = w_out_bf; j = i - NIN4; }
    else {
        j = i - NIN4 - NOUT4;
        int f = j * 4, n = f / D_INNER, k = f % D_INNER;
        ushort4 o = {0, 0, 0, 0};
        if (n < DT_RANK + 2 * D_STATE) {
            float4 v = *(const float4*)&xw[n * D_INNER + k];
            o.x = f2bf(v.x); o.y = f2bf(v.y); o.z = f2bf(v.z); o.w = f2bf(v.w);
        }
        ((ushort4*)w_xp_bf)[j] = o;
        return;
    }
    float4 v = ((const float4*)src)[j];
    ushort4 o;
    o.x = f2bf(v.x); o.y = f2bf(v.y); o.z = f2bf(v.z); o.w = f2bf(v.w);
    ((ushort4*)dst)[j] = o;
}

__global__ __launch_bounds__(256) void cast_bf16_v4(
    const float* __restrict__ in, unsigned short* __restrict__ out, int n4)
{
    int i = blockIdx.x * 256 + threadIdx.x;
    if (i >= n4) return;
    float4 v = ((const float4*)in)[i];
    ushort4 o;
    o.x = f2bf(v.x); o.y = f2bf(v.y); o.z = f2bf(v.z); o.w = f2bf(v.w);
    ((ushort4*)out)[i] = o;
}

// =====================================================================
// im2col (bf16 out) for 16x16 stride-16 patch conv
// =====================================================================
__global__ __launch_bounds__(256) void im2col_patch_bf16(
    const float* __restrict__ x, unsigned short* __restrict__ out)
{
    size_t idx = (size_t)blockIdx.x * 256 + threadIdx.x;
    if (idx >= BLD) return;
    int m = (int)(idx / D_MODEL);
    int k = (int)(idx % D_MODEL);
    int b = m / LSEQ, l = m % LSEQ;
    int ph = l / 14, pw = l % 14;
    int c = k >> 8, r = k & 255;
    int kh = r >> 4, kw = r & 15;
    out[idx] = f2bf(x[(((size_t)b * 3 + c) * IMG + ph * PATCHSZ + kh) * IMG + pw * PATCHSZ + kw]);
}

// =====================================================================
// LayerNorm over last dim (768). One block per (b,l) row.
// =====================================================================
template <bool BF16OUT>
__global__ __launch_bounds__(256) void layernorm_768(
    const float* __restrict__ x, const float* __restrict__ g,
    const float* __restrict__ b, void* __restrict__ optr)
{
    __shared__ float red[4];
    const size_t base = (size_t)blockIdx.x * D_MODEL;
    const int t = threadIdx.x;

    float v[3];
#pragma unroll
    for (int i = 0; i < 3; i++) v[i] = x[base + t + i * 256];

    float s = v[0] + v[1] + v[2];
#pragma unroll
    for (int off = 32; off > 0; off >>= 1) s += __shfl_down(s, off);
    if ((t & 63) == 0) red[t >> 6] = s;
    __syncthreads();
    float mu = (red[0] + red[1] + red[2] + red[3]) * (1.f / D_MODEL);
    __syncthreads();

    float q = 0.f;
#pragma unroll
    for (int i = 0; i < 3; i++) { float d = v[i] - mu; q += d * d; }
#pragma unroll
    for (int off = 32; off > 0; off >>= 1) q += __shfl_down(q, off);
    if ((t & 63) == 0) red[t >> 6] = q;
    __syncthreads();
    float var = (red[0] + red[1] + red[2] + red[3]) * (1.f / D_MODEL);
    float rs = rsqrtf(var + 1e-5f);

#pragma unroll
    for (int i = 0; i < 3; i++) {
        int d = t + i * 256;
        float o = (v[i] - mu) * rs * g[d] + b[d];
        if (BF16OUT) ((unsigned short*)optr)[base + d] = f2bf(o);
        else         ((float*)optr)[base + d] = o;
    }
}

// =====================================================================
// depthwise causal conv1d (k=4) + SiLU. xi rows stride 3072 (xz cols 0..1535).
// =====================================================================
__global__ __launch_bounds__(256) void conv1d_silu(
    const float* __restrict__ xi, const float* __restrict__ cw,
    const float* __restrict__ cb, unsigned short* __restrict__ xc)
{
    size_t idx = (size_t)blockIdx.x * 256 + threadIdx.x;
    if (idx >= BLDI) return;
    int m = (int)(idx / D_INNER);
    int e = (int)(idx % D_INNER);
    int b = m / LSEQ, l = m % LSEQ;
    float s = cb[e];
#pragma unroll
    for (int k = 0; k < D_CONV; k++) {
        int ll = l + k - (D_CONV - 1);
        if (ll >= 0)
            s = fmaf(xi[((size_t)b * LSEQ + ll) * 3072 + e], cw[e * D_CONV + k], s);
    }
    xc[idx] = f2bf(s / (1.f + expf(-s)));
}

// =====================================================================
// Selective scan v3: chunked LDS double-buffer. Block = 64 channels x
// 1 batch; thread = (channel dd = t>>2, state quad sq = t&3).
// Per chunk (28 steps): 6 uniform global_load_lds / thread stage the
// NEXT chunk while the current one computes from LDS; counted
// s_waitcnt vmcnt(6) + raw s_barrier (no vmcnt(0) drain in steady state).
// y (bf16) written in place of xc. grid (24, 32), 256 thr, 48 KiB LDS.
// =====================================================================
#define SCHUNK 28
#define NCHUNK 7
#define SS_DT 0
#define SS_Z  2048
#define SS_BC 4096
#define SS_XC 5120
#define SS_BUF 6144   // floats per buffer (24 KiB)

__device__ __forceinline__ void ss_stage(
    float* buf, int lbase, int t,
    const float* dtp, const float* zp, const unsigned short* xcp,
    const float* dblb, int d0, size_t rw0, size_t rx0)
{
    // dt: 512 units (2/thread), layout [28][64] f32 (padded to 2048 f)
    {
        int u = t;
        int l = u >> 4; l = l > SCHUNK - 1 ? SCHUNK - 1 : l;
        int dc = (u & 15) * 4;
        gload16(dtp + rw0 + (size_t)(lbase + l) * 3072 + d0 + dc, buf + SS_DT + u * 4);
        u = t + 256;
        l = u >> 4; l = l > SCHUNK - 1 ? SCHUNK - 1 : l;
        dc = (u & 15) * 4;
        gload16(dtp + rw0 + (size_t)(lbase + l) * 3072 + d0 + dc, buf + SS_DT + u * 4);
    }
    // z: 512 units (2/thread)
    {
        int u = t;
        int l = u >> 4; l = l > SCHUNK - 1 ? SCHUNK - 1 : l;
        int dc = (u & 15) * 4;
        gload16(zp + rw0 + (size_t)(lbase + l) * 3072 + d0 + dc, buf + SS_Z + u * 4);
        u = t + 256;
        l = u >> 4; l = l > SCHUNK - 1 ? SCHUNK - 1 : l;
        dc = (u & 15) * 4;
        gload16(zp + rw0 + (size_t)(lbase + l) * 3072 + d0 + dc, buf + SS_Z + u * 4);
    }
    // bc: 256 units (1/thread), layout [28][32] f32 (B cols 0..15, C 16..31)
    {
        int u = t;
        int l = u >> 3; l = l > SCHUNK - 1 ? SCHUNK - 1 : l;
        int cc = (u & 7) * 4;
        gload16(dblb + (size_t)(lbase + l) * XP_PAD + DT_RANK + cc, buf + SS_BC + u * 4);
    }
    // xc: 256 units (1/thread), layout [28][64] bf16
    {
        int u = t;
        int l = u >> 3; l = l > SCHUNK - 1 ? SCHUNK - 1 : l;
        int dc = (u & 7) * 8;
        gload16(xcp + rx0 + (size_t)(lbase + l) * D_INNER + d0 + dc,
                (unsigned short*)(buf + SS_XC) + u * 8);
    }
}

__global__ __launch_bounds__(256) void selective_scan(
    const float* __restrict__ dt,      // xz cols 0..1535, stride 3072
    unsigned short* xc,                // [BL][1536] bf16, in/out (y)
    const float* __restrict__ z,       // xz + 1536, stride 3072
    const float* __restrict__ dbl,     // [BL][128]
    const float* __restrict__ A_log, const float* __restrict__ Dp)
{
    __shared__ float lds[2 * SS_BUF];

    const int t = threadIdx.x;
    const int sq = t & 3;
    const int dd = t >> 2;
    const int d0 = blockIdx.x * 64;
    const int b = blockIdx.y;
    const int d = d0 + dd;

    const float4 av = *(const float4*)&A_log[d * D_STATE + sq * 4];
    const float a0 = -__expf(av.x), a1 = -__expf(av.y),
                a2 = -__expf(av.z), a3 = -__expf(av.w);
    const float dp = Dp[d];

    const float* dblb = dbl + (size_t)b * LSEQ * XP_PAD;
    const size_t rw0 = (size_t)b * LSEQ * 3072;
    const size_t rx0 = (size_t)b * LSEQ * D_INNER;

    float h0 = 0.f, h1 = 0.f, h2 = 0.f, h3 = 0.f;

    ss_stage(lds, 0, t, dt, z, xc, dblb, d0, rw0, rx0);

    for (int c = 0; c < NCHUNK; ++c) {
        const int p = c & 1;
        if (c + 1 < NCHUNK) {
            ss_stage(lds + (p ^ 1) * SS_BUF, (c + 1) * SCHUNK, t,
                     dt, z, xc, dblb, d0, rw0, rx0);
            asm volatile("s_waitcnt vmcnt(6)" ::: "memory");
        } else {
            asm volatile("s_waitcnt vmcnt(0)" ::: "memory");
        }
        __builtin_amdgcn_s_barrier();

        const float* buf = lds + p * SS_BUF;
        const unsigned short* xcs = (const unsigned short*)(buf + SS_XC);
        const int lbase = c * SCHUNK;
#pragma unroll 4
        for (int l = 0; l < SCHUNK; ++l) {
            const float dtc = buf[SS_DT + l * 64 + dd];
            const float zvc = buf[SS_Z + l * 64 + dd];
            const float xvc = bf2f(xcs[l * 64 + dd]);
            const float4 Bc = *(const float4*)&buf[SS_BC + l * 32 + sq * 4];
            const float4 Cc = *(const float4*)&buf[SS_BC + l * 32 + 16 + sq * 4];
            const float dtx = dtc * xvc;
            h0 = fmaf(__expf(dtc * a0), h0, dtx * Bc.x);
            h1 = fmaf(__expf(dtc * a1), h1, dtx * Bc.y);
            h2 = fmaf(__expf(dtc * a2), h2, dtx * Bc.z);
            h3 = fmaf(__expf(dtc * a3), h3, dtx * Bc.w);
            float py = fmaf(h0, Cc.x, fmaf(h1, Cc.y, fmaf(h2, Cc.z, h3 * Cc.w)));
            py += __shfl_xor(py, 1);
            py += __shfl_xor(py, 2);
            if (sq == 0) {
                const float yv = py + dp * xvc;
                const float sig = 1.f / (1.f + __expf(-zvc));
                xc[rx0 + (size_t)(lbase + l) * D_INNER + d] = f2bf(yv * zvc * sig);
            }
        }
        __builtin_amdgcn_s_barrier();
    }
}

// =====================================================================
// mean over L
// =====================================================================
__global__ __launch_bounds__(256) void pool_mean(
    const float* __restrict__ hn, float* __restrict__ pooled)
{
    int d = blockIdx.x * 256 + threadIdx.x;
    int b = blockIdx.y;
    if (d >= D_MODEL) return;
    float s = 0.f;
    for (int l = 0; l < LSEQ; l++)
        s += hn[((size_t)b * LSEQ + l) * D_MODEL + d];
    pooled[(size_t)b * D_MODEL + d] = s * (1.f / LSEQ);
}

// =====================================================================
static inline void gemm32(hipStream_t st, const float* A, int lda,
                          const float* W, const float* bias,
                          const float* res, float* C, int ldc,
                          int M, int N, int K, int act)
{
    dim3 g((M + TM - 1) / TM, (N + TN - 1) / TN);
    gemm_f32<<<g, 256, 0, st>>>(A, lda, W, bias, res, C, ldc, M, N, K, act);
}

static inline void gemmbf(hipStream_t st, const unsigned short* A,
                          const unsigned short* W, const float* bias,
                          const float* res, int ldr, float* C, int ldc,
                          int M, int N, int K)
{
    dim3 g(M / 128, N / 128);
    gemm_bf16<<<g, 256, 0, st>>>(A, W, bias, res, ldr, C, ldc, K);
}

extern "C" void kernel_launch(void* const* d_in, const int* in_sizes, int n_in,
                              void* d_out, int out_size, void* d_ws, size_t ws_size,
                              hipStream_t stream)
{
    const float* x       = (const float*)d_in[0];
    const float* patch_w = (const float*)d_in[1];
    const float* patch_b = (const float*)d_in[2];
    const float* ln_g    = (const float*)d_in[3];
    const float* ln_b    = (const float*)d_in[4];
    const float* in_w    = (const float*)d_in[5];
    const float* conv_w  = (const float*)d_in[6];
    const float* conv_b  = (const float*)d_in[7];
    const float* xp_w    = (const float*)d_in[8];
    const float* dt_w    = (const float*)d_in[9];
    const float* dt_b    = (const float*)d_in[10];
    const float* A_log   = (const float*)d_in[11];
    const float* Dp      = (const float*)d_in[12];
    const float* out_w   = (const float*)d_in[13];
    const float* fn_g    = (const float*)d_in[14];
    const float* fn_b    = (const float*)d_in[15];
    const float* head_w  = (const float*)d_in[16];
    const float* head_b  = (const float*)d_in[17];
    float* out = (float*)d_out;

    // ---- workspace layout (~137 MB) ----
    float* wf = (float*)d_ws;
    float* h      = wf;                           // BL x 768
    float* xz     = h + BLD;                      // BL x 3072 (xi|z; dt reuses xi; final-LN out)
    float* dbl    = xz + (size_t)BL * 3072;       // BL x 128
    float* pooled = dbl + (size_t)BL * XP_PAD;    // 32 x 768
    unsigned short* us = (unsigned short*)(pooled + (size_t)BATCH * D_MODEL);
    unsigned short* hn_bf   = us;                             // BL x 768 (also im2col buf)
    unsigned short* xc_bf   = hn_bf + BLD;                    // BL x 1536 (xc, then y in place)
    unsigned short* w_in_bf = xc_bf + BLDI;                   // 3072 x 768
    unsigned short* w_out_bf= w_in_bf + (size_t)2 * D_INNER * D_MODEL;   // 768 x 1536
    unsigned short* w_xp_bf = w_out_bf + (size_t)D_MODEL * D_INNER;      // 128 x 1536 (padded)
    unsigned short* w_pt_bf = w_xp_bf + (size_t)XP_PAD * D_INNER;        // 768 x 768

    float* dtbuf = xz;          // dt overwrites xi (xz cols 0..1535)
    float* zptr  = xz + D_INNER;
    float* fln   = xz;          // final LN output (xz free then)

    // ---- patch embed ----
    cast_bf16_v4<<<(D_MODEL * D_MODEL / 4 + 255) / 256, 256, 0, stream>>>(
        patch_w, w_pt_bf, D_MODEL * D_MODEL / 4);
    im2col_patch_bf16<<<(unsigned)((BLD + 255) / 256), 256, 0, stream>>>(x, hn_bf);
    gemmbf(stream, hn_bf, w_pt_bf, patch_b, nullptr, 0, h, D_MODEL,
           BL, D_MODEL, D_MODEL);

    // ---- mamba blocks ----
    for (int layer = 0; layer < DEPTH; layer++) {
        const float* lg  = ln_g + (size_t)layer * D_MODEL;
        const float* lb  = ln_b + (size_t)layer * D_MODEL;
        const float* iw  = in_w + (size_t)layer * 2 * D_INNER * D_MODEL;
        const float* cw  = conv_w + (size_t)layer * D_INNER * D_CONV;
        const float* cb  = conv_b + (size_t)layer * D_INNER;
        const float* xw  = xp_w + (size_t)layer * (DT_RANK + 2 * D_STATE) * D_INNER;
        const float* dw  = dt_w + (size_t)layer * D_INNER * DT_RANK;
        const float* db  = dt_b + (size_t)layer * D_INNER;
        const float* al  = A_log + (size_t)layer * D_INNER * D_STATE;
        const float* dpp = Dp + (size_t)layer * D_INNER;
        const float* ow  = out_w + (size_t)layer * D_MODEL * D_INNER;

        // cast this layer's weights (merged, one launch)
        cast_layer<<<NCAST4 / 256, 256, 0, stream>>>(
            iw, ow, xw, w_in_bf, w_out_bf, w_xp_bf);

        // LN -> bf16
        layernorm_768<true><<<BL, 256, 0, stream>>>(h, lg, lb, hn_bf);

        // in_proj (one GEMM, N=3072) -> xz fp32
        gemmbf(stream, hn_bf, w_in_bf, nullptr, nullptr, 0, xz, 2 * D_INNER,
               BL, 2 * D_INNER, D_MODEL);

        // conv + silu -> xc bf16
        conv1d_silu<<<(unsigned)((BLDI + 255) / 256), 256, 0, stream>>>(xz, cw, cb, xc_bf);

        // x_proj -> dbl fp32 (N padded to 128)
        gemmbf(stream, xc_bf, w_xp_bf, nullptr, nullptr, 0, dbl, XP_PAD,
               BL, XP_PAD, D_INNER);

        // dt = softplus(dbl[:, :48] @ dt_w^T + dt_b) -> xz cols 0..1535
        gemm32(stream, dbl, XP_PAD, dw, db, nullptr, dtbuf, 2 * D_INNER,
               BL, D_INNER, DT_RANK, 1);

        // selective scan (+Dp*xc, *silu(z)); y bf16 in place of xc
        dim3 sg(D_INNER / 64, BATCH);
        selective_scan<<<sg, 256, 0, stream>>>(dtbuf, xc_bf, zptr, dbl, al, dpp);

        // out_proj + residual -> h
        gemmbf(stream, xc_bf, w_out_bf, nullptr, h, D_MODEL, h, D_MODEL,
               BL, D_MODEL, D_INNER);
    }

    // ---- final LN + mean + head ----
    layernorm_768<false><<<BL, 256, 0, stream>>>(h, fn_g, fn_b, fln);
    dim3 pg(3, BATCH);
    pool_mean<<<pg, 256, 0, stream>>>(fln, pooled);
    gemm32(stream, pooled, D_MODEL, head_w, head_b, nullptr, out, NUM_CLASSES,
           BATCH, NUM_CLASSES, D_MODEL, 0);
}